// Round 3
// baseline (295.069 us; speedup 1.0000x reference)
//
#include <hip/hip_runtime.h>
#include <cstdint>

// MambaBlock: out = (silu(x@in_w[:1024]^T + b0) * silu(x@in_w[1024:]^T + b1)) @ out_w^T + out_b
// M = 32768, D = K = 1024. dt_w/dt_b/A/Dp are dead inputs.
//
// Structure: 256x256 tile, BK=32, 512 threads (8 waves, 2Mx4N), triple-buffered
// LDS (96 KiB), prefetch depth 2, counted vmcnt(4) (never 0 in main loop),
// T2 swizzle via pre-swizzled global source + swizzled ds_read (verified: 0
// bank conflicts), and NEW this round: 2-phase fine interleave per K-tile
// (16 MFMA per phase, s_barrier + lgkmcnt(0) + setprio around each cluster)
// per the m201 8-phase template granularity.

typedef __bf16 bf16x8 __attribute__((ext_vector_type(8)));
typedef float f32x4 __attribute__((ext_vector_type(4)));

#define KD 1024
#define BUF_ELEMS 16384  // (256*32 A + 256*32 B) elems per buffer

__device__ __forceinline__ void gload_lds16(const void* g, void* lds_u) {
  __builtin_amdgcn_global_load_lds(
      (__attribute__((address_space(1))) void*)(uintptr_t)g,
      (__attribute__((address_space(3))) void*)(uint32_t)(uintptr_t)lds_u,
      16, 0, 0);
}

__device__ __forceinline__ float silu_f(float v) {
  return v / (1.0f + __expf(-v));
}

#define WAITB(N) do { \
  asm volatile("s_waitcnt vmcnt(" #N ")" ::: "memory"); \
  asm volatile("s_barrier" ::: "memory"); } while (0)

// ---------------- casts ----------------
__global__ void cast_f32_to_bf16_x8(const float* __restrict__ in,
                                    __bf16* __restrict__ out, int n8) {
  int i = blockIdx.x * blockDim.x + threadIdx.x;
  if (i >= n8) return;
  const float4* p = (const float4*)in;
  float4 v0 = p[2 * i];
  float4 v1 = p[2 * i + 1];
  bf16x8 o;
  o[0] = (__bf16)v0.x; o[1] = (__bf16)v0.y; o[2] = (__bf16)v0.z; o[3] = (__bf16)v0.w;
  o[4] = (__bf16)v1.x; o[5] = (__bf16)v1.y; o[6] = (__bf16)v1.z; o[7] = (__bf16)v1.w;
  ((bf16x8*)out)[i] = o;
}

// W1' row 2c = in_w row c (x_val), row 2c+1 = in_w row 1024+c (res)
__global__ void cast_w1_interleave(const float* __restrict__ in,
                                   __bf16* __restrict__ out) {
  int i = blockIdx.x * blockDim.x + threadIdx.x;  // 2048*128 threads
  int orow = i >> 7;
  int chunk = i & 127;
  int srow = (orow >> 1) + ((orow & 1) << 10);
  const float4* p = (const float4*)(in + ((size_t)srow << 10) + (chunk << 3));
  float4 v0 = p[0], v1 = p[1];
  bf16x8 o;
  o[0] = (__bf16)v0.x; o[1] = (__bf16)v0.y; o[2] = (__bf16)v0.z; o[3] = (__bf16)v0.w;
  o[4] = (__bf16)v1.x; o[5] = (__bf16)v1.y; o[6] = (__bf16)v1.z; o[7] = (__bf16)v1.w;
  *(bf16x8*)(out + ((size_t)orow << 10) + (chunk << 3)) = o;
}

// ---------------- GEMM core ----------------
// Stage one 256x32 K-tile of A and B into buffer BUF. Per thread: 4 gloads.
// Global source chunk pre-swizzled: lane l covers LDS slot (row l>>2, slot l&3)
// which must hold global chunk (l&3)^((l>>3)&3)  [= slot ^ ((row>>1)&3)].
template <int BUF>
__device__ __forceinline__ void stage_tile(const __bf16*& pa, const __bf16*& pb,
                                           __bf16* smw) {
  __bf16* d = smw + BUF * BUF_ELEMS;
  gload_lds16(pa, d);
  gload_lds16(pa + 128 * KD, d + 4096);
  gload_lds16(pb, d + 8192);
  gload_lds16(pb + 128 * KD, d + 12288);
  pa += 32;
  pb += 32;
}

// 2-phase fine interleave: phase A = {8 ds_read, barrier, lgkm0, 16 MFMA},
// phase B = {4 ds_read, barrier, lgkm0, 16 MFMA}. B-frags live across both.
template <int BUF>
__device__ __forceinline__ void compute_tile(const __bf16* sm, int aoff, int boff,
                                             f32x4 (&acc)[8][4]) {
  const __bf16* base = sm + BUF * BUF_ELEMS;
  bf16x8 af[4], bf[4];
  // ---- phase A ----
#pragma unroll
  for (int j = 0; j < 4; ++j)
    bf[j] = *(const bf16x8*)(base + boff + j * 512);
#pragma unroll
  for (int i = 0; i < 4; ++i)
    af[i] = *(const bf16x8*)(base + aoff + i * 512);
  __builtin_amdgcn_s_barrier();
  asm volatile("s_waitcnt lgkmcnt(0)" ::: "memory");
  __builtin_amdgcn_sched_barrier(0);
  __builtin_amdgcn_s_setprio(1);
#pragma unroll
  for (int i = 0; i < 4; ++i)
#pragma unroll
    for (int j = 0; j < 4; ++j)
      acc[i][j] = __builtin_amdgcn_mfma_f32_16x16x32_bf16(af[i], bf[j], acc[i][j], 0, 0, 0);
  __builtin_amdgcn_s_setprio(0);
  // ---- phase B ----
#pragma unroll
  for (int i = 0; i < 4; ++i)
    af[i] = *(const bf16x8*)(base + aoff + (i + 4) * 512);
  __builtin_amdgcn_s_barrier();
  asm volatile("s_waitcnt lgkmcnt(0)" ::: "memory");
  __builtin_amdgcn_sched_barrier(0);
  __builtin_amdgcn_s_setprio(1);
#pragma unroll
  for (int i = 0; i < 4; ++i)
#pragma unroll
    for (int j = 0; j < 4; ++j)
      acc[i + 4][j] = __builtin_amdgcn_mfma_f32_16x16x32_bf16(af[i], bf[j], acc[i + 4][j], 0, 0, 0);
  __builtin_amdgcn_s_setprio(0);
}

// Fills acc for the 256x256 tile at (m0, n0). A:[M][1024], B:[N_rows][1024].
__device__ __forceinline__ void gemm_core(const __bf16* __restrict__ A,
                                          const __bf16* __restrict__ B,
                                          __bf16* sm, long m0, long n0,
                                          f32x4 (&acc)[8][4]) {
  const int t = threadIdx.x;
  const int w = t >> 6;
  const int lane = t & 63;
  const int lr = lane & 15;
  const int lk = lane >> 4;
  const int wr = w >> 2;  // 0..1 (M)
  const int wc = w & 3;   // 0..3 (N)

  // staging source (per thread, swizzled chunk)
  const int l = lane;
  const int stg_row = w * 16 + (l >> 2);
  const int stg_col = ((l & 3) ^ ((l >> 3) & 3)) << 3;
  const __bf16* pa = A + (m0 + stg_row) * KD + stg_col;
  const __bf16* pb = B + (n0 + stg_row) * KD + stg_col;
  __bf16* smw = sm + w * 512;  // wave-uniform LDS base (1024B per wave-instr)

  // fragment read offsets (elements), swizzled slot = lk ^ ((lr>>1)&3)
  const int swz8 = (lk ^ ((lr >> 1) & 3)) << 3;
  const int aoff = (wr * 128 + lr) * 32 + swz8;          // + i*512
  const int boff = 8192 + (wc * 64 + lr) * 32 + swz8;    // + j*512

#pragma unroll
  for (int i = 0; i < 8; ++i)
#pragma unroll
    for (int j = 0; j < 4; ++j)
      acc[i][j] = (f32x4){0.f, 0.f, 0.f, 0.f};

  // prologue: stage tiles 0,1
  stage_tile<0>(pa, pb, smw);
  stage_tile<1>(pa, pb, smw);

  // tiles 0..29: compute buf t%3, stage tile t+2 into buf (t+2)%3
  for (int it = 0; it < 10; ++it) {
    WAITB(4); stage_tile<2>(pa, pb, smw); compute_tile<0>(sm, aoff, boff, acc);
    WAITB(4); stage_tile<0>(pa, pb, smw); compute_tile<1>(sm, aoff, boff, acc);
    WAITB(4); stage_tile<1>(pa, pb, smw); compute_tile<2>(sm, aoff, boff, acc);
  }
  // tail: tiles 30 (buf0), 31 (buf1)
  WAITB(4); compute_tile<0>(sm, aoff, boff, acc);
  WAITB(0); compute_tile<1>(sm, aoff, boff, acc);
}

// ---------------- GEMM1: Y = X @ W1'^T, pair-silu epilogue -> G bf16 ----------
// N_total = 2048 (interleaved); output G cols = 1024.
__global__ __launch_bounds__(512, 2)
void gemm1_silu(const __bf16* __restrict__ X, const __bf16* __restrict__ W1i,
                const float* __restrict__ in_b, __bf16* __restrict__ G) {
  __shared__ __bf16 sm[3 * BUF_ELEMS];
  // XCD-aware bijective swizzle: nwg = 128*8 = 1024, divisible by 8
  const int bid = blockIdx.x;
  const int swz = (bid & 7) * 128 + (bid >> 3);
  const int m_idx = swz >> 3;   // / 8 n-blocks
  const int n_idx = swz & 7;
  const long m0 = (long)m_idx * 256;
  const long n0 = (long)n_idx * 256;

  f32x4 acc[8][4];
  gemm_core(X, W1i, sm, m0, n0, acc);

  const int lane = threadIdx.x & 63;
  const int w = threadIdx.x >> 6;
  const int wr = w >> 2, wc = w & 3;

  float bj[4];
#pragma unroll
  for (int j = 0; j < 4; ++j) {
    int nn = (int)n0 + wc * 64 + j * 16 + (lane & 15);
    bj[j] = (nn & 1) ? in_b[1024 + (nn >> 1)] : in_b[nn >> 1];
  }
#pragma unroll
  for (int i = 0; i < 8; ++i)
#pragma unroll
    for (int j = 0; j < 4; ++j)
#pragma unroll
      for (int q = 0; q < 4; ++q) {
        int r = wr * 128 + i * 16 + (lane >> 4) * 4 + q;
        float v = acc[i][j][q] + bj[j];
        float s = silu_f(v);
        float p = __shfl_xor(s, 1);
        float g = s * p;
        if (!(lane & 1)) {
          int nn = (int)n0 + wc * 64 + j * 16 + (lane & 15);
          G[(m0 + r) * 1024 + (nn >> 1)] = (__bf16)g;
        }
      }
}

// ---------------- GEMM2: OUT = G @ W2^T + out_b (fp32) ----------------
__global__ __launch_bounds__(512, 2)
void gemm2_bias(const __bf16* __restrict__ G, const __bf16* __restrict__ W2,
                const float* __restrict__ out_b, float* __restrict__ OUT) {
  __shared__ __bf16 sm[3 * BUF_ELEMS];
  // nwg = 128*4 = 512, divisible by 8
  const int bid = blockIdx.x;
  const int swz = (bid & 7) * 64 + (bid >> 3);
  const int m_idx = swz >> 2;   // / 4 n-blocks
  const int n_idx = swz & 3;
  const long m0 = (long)m_idx * 256;
  const long n0 = (long)n_idx * 256;

  f32x4 acc[8][4];
  gemm_core(G, W2, sm, m0, n0, acc);

  const int lane = threadIdx.x & 63;
  const int w = threadIdx.x >> 6;
  const int wr = w >> 2, wc = w & 3;

  float ob[4];
#pragma unroll
  for (int j = 0; j < 4; ++j)
    ob[j] = out_b[(int)n0 + wc * 64 + j * 16 + (lane & 15)];
#pragma unroll
  for (int i = 0; i < 8; ++i)
#pragma unroll
    for (int j = 0; j < 4; ++j)
#pragma unroll
      for (int q = 0; q < 4; ++q) {
        int r = wr * 128 + i * 16 + (lane >> 4) * 4 + q;
        int c = wc * 64 + j * 16 + (lane & 15);
        OUT[(m0 + r) * 1024 + n0 + c] = acc[i][j][q] + ob[j];
      }
}

extern "C" void kernel_launch(void* const* d_in, const int* in_sizes, int n_in,
                              void* d_out, int out_size, void* d_ws, size_t ws_size,
                              hipStream_t stream) {
  const float* x = (const float*)d_in[0];
  const float* in_w = (const float*)d_in[1];
  const float* in_b = (const float*)d_in[2];
  const float* out_w = (const float*)d_in[3];
  const float* out_b = (const float*)d_in[4];
  // d_in[5..8] (dt_w, dt_b, A, Dp) are dead in the reference.

  char* ws = (char*)d_ws;
  __bf16* xb = (__bf16*)(ws);                       // 67108864 B
  __bf16* w1b = (__bf16*)(ws + (size_t)67108864);   //  4194304 B (interleaved)
  __bf16* w2b = (__bf16*)(ws + (size_t)71303168);   //  2097152 B
  __bf16* gb = (__bf16*)(ws + (size_t)73400320);    // 67108864 B

  cast_f32_to_bf16_x8<<<dim3(16384), 256, 0, stream>>>(x, xb, 33554432 / 8);
  cast_w1_interleave<<<dim3(1024), 256, 0, stream>>>(in_w, w1b);
  cast_f32_to_bf16_x8<<<dim3(512), 256, 0, stream>>>(out_w, w2b, 1048576 / 8);

  gemm1_silu<<<dim3(1024), 512, 0, stream>>>(xb, w1b, in_b, gb);
  gemm2_bias<<<dim3(512), 512, 0, stream>>>(gb, w2b, out_b, (float*)d_out);
}

// Round 4
// 287.970 us; speedup vs baseline: 1.0246x; 1.0246x over previous
//
#include <hip/hip_runtime.h>
#include <cstdint>

// MambaBlock: out = (silu(x@in_w[:1024]^T+b0) * silu(x@in_w[1024:]^T+b1)) @ out_w^T + out_b
// M = 32768, K = 1024. dt_w/dt_b/A/Dp are dead inputs.
//
// Faithful m201 8-phase template port: 256x256 tile, BK=64, 8 waves (2Mx4N),
// 2 LDS buffers x 64 KiB (A[256][64]+B[256][64]); iter = 2 K-tiles = 8 phases;
// each phase {ds_reads, stage, barrier, lgkmcnt(0)+sched_barrier, setprio(1),
// 16 MFMA, setprio(0), barrier}. B-frags persist per K-tile (24 b128/wave/K-tile).
// Swizzle: phys_chunk = chunk ^ (row&7) on both global-source and ds_read
// (G4 recipe for 128-B rows). Staging: buf for next half staged in ph1-2 with
// >=2-phase lead; vmcnt(0) at ph4/ph8 end before trailing barrier.

typedef __bf16 bf16x8 __attribute__((ext_vector_type(8)));
typedef float f32x4 __attribute__((ext_vector_type(4)));

#define KD 1024

__device__ __forceinline__ void gload_lds16(const void* g, void* lds_u) {
  __builtin_amdgcn_global_load_lds(
      (__attribute__((address_space(1))) void*)(uintptr_t)g,
      (__attribute__((address_space(3))) void*)(uint32_t)(uintptr_t)lds_u,
      16, 0, 0);
}

__device__ __forceinline__ float silu_f(float v) {
  return v / (1.0f + __expf(-v));
}

// ---------------- casts ----------------
__global__ void cast_f32_to_bf16_x8(const float* __restrict__ in,
                                    __bf16* __restrict__ out, int n8) {
  int i = blockIdx.x * blockDim.x + threadIdx.x;
  if (i >= n8) return;
  const float4* p = (const float4*)in;
  float4 v0 = p[2 * i];
  float4 v1 = p[2 * i + 1];
  bf16x8 o;
  o[0] = (__bf16)v0.x; o[1] = (__bf16)v0.y; o[2] = (__bf16)v0.z; o[3] = (__bf16)v0.w;
  o[4] = (__bf16)v1.x; o[5] = (__bf16)v1.y; o[6] = (__bf16)v1.z; o[7] = (__bf16)v1.w;
  ((bf16x8*)out)[i] = o;
}

// W1' row 2c = in_w row c (x_val), row 2c+1 = in_w row 1024+c (res)
__global__ void cast_w1_interleave(const float* __restrict__ in,
                                   __bf16* __restrict__ out) {
  int i = blockIdx.x * blockDim.x + threadIdx.x;  // 2048*128 threads
  int orow = i >> 7;
  int chunk = i & 127;
  int srow = (orow >> 1) + ((orow & 1) << 10);
  const float4* p = (const float4*)(in + ((size_t)srow << 10) + (chunk << 3));
  float4 v0 = p[0], v1 = p[1];
  bf16x8 o;
  o[0] = (__bf16)v0.x; o[1] = (__bf16)v0.y; o[2] = (__bf16)v0.z; o[3] = (__bf16)v0.w;
  o[4] = (__bf16)v1.x; o[5] = (__bf16)v1.y; o[6] = (__bf16)v1.z; o[7] = (__bf16)v1.w;
  *(bf16x8*)(out + ((size_t)orow << 10) + (chunk << 3)) = o;
}

// ---------------- GEMM core helpers ----------------
// Stage 256 rows x 64 K-elems of one operand (32 KiB) = 4 wave-instrs/wave.
// psrc: per-lane global base (includes m0/n0, k, and swizzled chunk).
// smdst: per-wave LDS dest base (region + w*512 elems).
__device__ __forceinline__ void stage4(const __bf16* psrc, __bf16* smdst) {
  gload_lds16(psrc,          smdst);
  gload_lds16(psrc + 65536,  smdst + 4096);   // +64 rows
  gload_lds16(psrc + 131072, smdst + 8192);
  gload_lds16(psrc + 196608, smdst + 12288);
}

#define MFMA16(I0)                                                              \
  do {                                                                          \
    _Pragma("unroll") for (int a2 = 0; a2 < 2; ++a2) {                          \
      _Pragma("unroll") for (int jn = 0; jn < 4; ++jn) {                        \
        acc[(I0) + a2][jn] = __builtin_amdgcn_mfma_f32_16x16x32_bf16(           \
            af[a2][0], bf[jn][0], acc[(I0) + a2][jn], 0, 0, 0);                 \
        acc[(I0) + a2][jn] = __builtin_amdgcn_mfma_f32_16x16x32_bf16(           \
            af[a2][1], bf[jn][1], acc[(I0) + a2][jn], 0, 0, 0);                 \
      }                                                                         \
    }                                                                           \
  } while (0)

#define RD_A(ai, i)                                                             \
  do {                                                                          \
    af[ai][0] = *(const bf16x8*)(Bp + aBase + (i) * 1024 + o0);                 \
    af[ai][1] = *(const bf16x8*)(Bp + aBase + (i) * 1024 + o1);                 \
  } while (0)

#define PH_ENTER()                                                              \
  do {                                                                          \
    __builtin_amdgcn_s_barrier();                                               \
    asm volatile("s_waitcnt lgkmcnt(0)" ::: "memory");                          \
    __builtin_amdgcn_sched_barrier(0);                                          \
    __builtin_amdgcn_s_setprio(1);                                              \
  } while (0)

#define PH_EXIT()                                                               \
  do {                                                                          \
    __builtin_amdgcn_s_setprio(0);                                              \
    __builtin_amdgcn_s_barrier();                                               \
  } while (0)

// One half-iter: compute one K-tile (K=64) from buffer BUFE; optionally stage
// the OTHER buffer (pa_st/pb_st already include the stage K offset).
template <int BUFE>
__device__ __forceinline__ void compute_half(
    const __bf16* sm, int aBase, int bBase, int o0, int o1, f32x4 (&acc)[8][4],
    const __bf16* pa_st, const __bf16* pb_st, __bf16* smA_st, __bf16* smB_st,
    bool do_stage) {
  const __bf16* Bp = sm + BUFE;
  bf16x8 bf[4][2], af[2][2];
  // ---- ph1: B all + A i0,i1; stage A of other buffer ----
#pragma unroll
  for (int jn = 0; jn < 4; ++jn) {
    bf[jn][0] = *(const bf16x8*)(Bp + bBase + jn * 1024 + o0);
    bf[jn][1] = *(const bf16x8*)(Bp + bBase + jn * 1024 + o1);
  }
  RD_A(0, 0);
  RD_A(1, 1);
  asm volatile("s_waitcnt lgkmcnt(8)" ::: "memory");
  if (do_stage) stage4(pa_st, smA_st);
  PH_ENTER();
  MFMA16(0);
  PH_EXIT();
  // ---- ph2: A i2,i3; stage B of other buffer ----
  RD_A(0, 2);
  RD_A(1, 3);
  if (do_stage) stage4(pb_st, smB_st);
  PH_ENTER();
  MFMA16(2);
  PH_EXIT();
  // ---- ph3: A i4,i5 ----
  RD_A(0, 4);
  RD_A(1, 5);
  PH_ENTER();
  MFMA16(4);
  PH_EXIT();
  // ---- ph4: A i6,i7; vmcnt(0) before trailing barrier (staged loads have
  // >=2-phase lead; all waves' stages land before anyone reads them) ----
  RD_A(0, 6);
  RD_A(1, 7);
  PH_ENTER();
  MFMA16(6);
  __builtin_amdgcn_s_setprio(0);
  asm volatile("s_waitcnt vmcnt(0)" ::: "memory");
  __builtin_amdgcn_s_barrier();
}

// Fills acc for the 256x256 tile at (m0, n0). A:[M][1024], B:[Nrows][1024].
__device__ __forceinline__ void gemm_core(const __bf16* __restrict__ A,
                                          const __bf16* __restrict__ B,
                                          __bf16* sm, long m0, long n0,
                                          f32x4 (&acc)[8][4]) {
  const int t = threadIdx.x;
  const int w = t >> 6;
  const int lane = t & 63;
  const int lr = lane & 15;
  const int lk = lane >> 4;
  const int wr = w >> 2;  // 0..1 (M)
  const int wc = w & 3;   // 0..3 (N)

  // fragment-read addressing (elements). Row r's chunks are XOR-swizzled by
  // (r&7); for frag reads r&7 == lr&7.
  const int sw = lr & 7;
  const int o0 = (lk ^ sw) << 3;
  const int o1 = o0 ^ 32;
  const int aBase = (wr * 128 + lr) * 64;          // within A region; +i*1024
  const int bBase = 16384 + (wc * 64 + lr) * 64;   // within B region; +jn*1024

  // staging source: lane l covers LDS row (w*8 + l>>3), phys chunk l&7, which
  // holds global chunk (l&7)^(l>>3)  [row&7 == l>>3].
  const int grow = lane >> 3;
  const int gchk = ((lane & 7) ^ grow) << 3;
  const __bf16* pa = A + (m0 + w * 8 + grow) * KD + gchk;
  const __bf16* pb = B + (n0 + w * 8 + grow) * KD + gchk;

  // stage dests (per-wave): buf0 at elems 0, buf1 at 32768; B region +16384.
  __bf16* smA0 = sm + w * 512;
  __bf16* smB0 = sm + 16384 + w * 512;
  __bf16* smA1 = sm + 32768 + w * 512;
  __bf16* smB1 = sm + 32768 + 16384 + w * 512;

#pragma unroll
  for (int i = 0; i < 8; ++i)
#pragma unroll
    for (int j = 0; j < 4; ++j)
      acc[i][j] = (f32x4){0.f, 0.f, 0.f, 0.f};

  // prologue: stage K-tile 0 into buf0
  stage4(pa, smA0);
  stage4(pb, smB0);
  asm volatile("s_waitcnt vmcnt(0)" ::: "memory");
  __builtin_amdgcn_s_barrier();

  for (int it = 0; it < 8; ++it) {
    // half A: compute buf0 (K=it*128..+63); stage buf1 (K=it*128+64)
    compute_half<0>(sm, aBase, bBase, o0, o1, acc,
                    pa + it * 128 + 64, pb + it * 128 + 64, smA1, smB1, true);
    // half B: compute buf1 (K=it*128+64..); stage buf0 (K=(it+1)*128)
    compute_half<32768>(sm, aBase, bBase, o0, o1, acc,
                        pa + (it + 1) * 128, pb + (it + 1) * 128, smA0, smB0,
                        it < 7);
  }
}

// ---------------- GEMM1: Y = X @ W1'^T, pair-silu epilogue -> G bf16 --------
__global__ __launch_bounds__(512, 2)
void gemm1_silu(const __bf16* __restrict__ X, const __bf16* __restrict__ W1i,
                const float* __restrict__ in_b, __bf16* __restrict__ G) {
  __shared__ __bf16 sm[65536];  // 128 KiB: 2 buffers x (A 32K + B 32K bytes)
  // XCD-aware bijective swizzle: nwg = 128*8 = 1024, divisible by 8
  const int bid = blockIdx.x;
  const int swz = (bid & 7) * 128 + (bid >> 3);
  const long m0 = (long)(swz >> 3) * 256;
  const long n0 = (long)(swz & 7) * 256;

  f32x4 acc[8][4];
  gemm_core(X, W1i, sm, m0, n0, acc);

  const int lane = threadIdx.x & 63;
  const int w = threadIdx.x >> 6;
  const int wr = w >> 2, wc = w & 3;

  float bj[4];
#pragma unroll
  for (int j = 0; j < 4; ++j) {
    int nn = (int)n0 + wc * 64 + j * 16 + (lane & 15);
    bj[j] = (nn & 1) ? in_b[1024 + (nn >> 1)] : in_b[nn >> 1];
  }
#pragma unroll
  for (int i = 0; i < 8; ++i)
#pragma unroll
    for (int j = 0; j < 4; ++j)
#pragma unroll
      for (int q = 0; q < 4; ++q) {
        int r = wr * 128 + i * 16 + (lane >> 4) * 4 + q;
        float v = acc[i][j][q] + bj[j];
        float s = silu_f(v);
        float p = __shfl_xor(s, 1);
        float g = s * p;
        if (!(lane & 1)) {
          int nn = (int)n0 + wc * 64 + j * 16 + (lane & 15);
          G[(m0 + r) * 1024 + (nn >> 1)] = (__bf16)g;
        }
      }
}

// ---------------- GEMM2: OUT = G @ W2^T + out_b (fp32) ----------------
__global__ __launch_bounds__(512, 2)
void gemm2_bias(const __bf16* __restrict__ G, const __bf16* __restrict__ W2,
                const float* __restrict__ out_b, float* __restrict__ OUT) {
  __shared__ __bf16 sm[65536];
  // nwg = 128*4 = 512, divisible by 8
  const int bid = blockIdx.x;
  const int swz = (bid & 7) * 64 + (bid >> 3);
  const long m0 = (long)(swz >> 2) * 256;
  const long n0 = (long)(swz & 3) * 256;

  f32x4 acc[8][4];
  gemm_core(G, W2, sm, m0, n0, acc);

  const int lane = threadIdx.x & 63;
  const int w = threadIdx.x >> 6;
  const int wr = w >> 2, wc = w & 3;

  float ob[4];
#pragma unroll
  for (int j = 0; j < 4; ++j)
    ob[j] = out_b[(int)n0 + wc * 64 + j * 16 + (lane & 15)];
#pragma unroll
  for (int i = 0; i < 8; ++i)
#pragma unroll
    for (int j = 0; j < 4; ++j)
#pragma unroll
      for (int q = 0; q < 4; ++q) {
        int r = wr * 128 + i * 16 + (lane >> 4) * 4 + q;
        int c = wc * 64 + j * 16 + (lane & 15);
        OUT[(m0 + r) * 1024 + n0 + c] = acc[i][j][q] + ob[j];
      }
}

extern "C" void kernel_launch(void* const* d_in, const int* in_sizes, int n_in,
                              void* d_out, int out_size, void* d_ws, size_t ws_size,
                              hipStream_t stream) {
  const float* x = (const float*)d_in[0];
  const float* in_w = (const float*)d_in[1];
  const float* in_b = (const float*)d_in[2];
  const float* out_w = (const float*)d_in[3];
  const float* out_b = (const float*)d_in[4];
  // d_in[5..8] (dt_w, dt_b, A, Dp) are dead in the reference.

  char* ws = (char*)d_ws;
  __bf16* xb = (__bf16*)(ws);                       // 67108864 B
  __bf16* w1b = (__bf16*)(ws + (size_t)67108864);   //  4194304 B (interleaved)
  __bf16* w2b = (__bf16*)(ws + (size_t)71303168);   //  2097152 B
  __bf16* gb = (__bf16*)(ws + (size_t)73400320);    // 67108864 B

  cast_f32_to_bf16_x8<<<dim3(16384), 256, 0, stream>>>(x, xb, 33554432 / 8);
  cast_w1_interleave<<<dim3(1024), 256, 0, stream>>>(in_w, w1b);
  cast_f32_to_bf16_x8<<<dim3(512), 256, 0, stream>>>(out_w, w2b, 1048576 / 8);

  gemm1_silu<<<dim3(1024), 512, 0, stream>>>(xb, w1b, in_b, gb);
  gemm2_bias<<<dim3(512), 512, 0, stream>>>(gb, w2b, out_b, (float*)d_out);
}

// Round 5
// 271.352 us; speedup vs baseline: 1.0874x; 1.0612x over previous
//
#include <hip/hip_runtime.h>
#include <cstdint>

// MambaBlock: out = (silu(x@in_w[:1024]^T+b0) * silu(x@in_w[1024:]^T+b1)) @ out_w^T + out_b
// M = 32768, K = 1024. dt_w/dt_b/A/Dp are dead inputs.
//
// Core (r2-proven): 256x256 tile, BK=32, 512 threads (8 waves, 2Mx4N), triple-
// buffered LDS (96 KiB), prefetch depth 2, counted vmcnt(4) (never 0 in main
// loop), T2 swizzle via pre-swizzled global source + swizzled ds_read (0 bank
// conflicts measured), setprio around MFMA cluster, bijective XCD swizzle.
// Round 5: 32x32x16 MFMA (2382 TF ceiling vs 2075, half the instr issue) +
// block-32 W1 interleave for a shuffle-free paired-silu epilogue (1 rcp/pair).

typedef __bf16 bf16x8 __attribute__((ext_vector_type(8)));
typedef float f32x16 __attribute__((ext_vector_type(16)));

#define KD 1024
#define BUF_ELEMS 16384  // (256*32 A + 256*32 B) elems per buffer

__device__ __forceinline__ void gload_lds16(const void* g, void* lds_u) {
  __builtin_amdgcn_global_load_lds(
      (__attribute__((address_space(1))) void*)(uintptr_t)g,
      (__attribute__((address_space(3))) void*)(uint32_t)(uintptr_t)lds_u,
      16, 0, 0);
}

#define WAITB(N) do { \
  asm volatile("s_waitcnt vmcnt(" #N ")" ::: "memory"); \
  asm volatile("s_barrier" ::: "memory"); } while (0)

// ---------------- casts ----------------
__global__ void cast_f32_to_bf16_x8(const float* __restrict__ in,
                                    __bf16* __restrict__ out, int n8) {
  int i = blockIdx.x * blockDim.x + threadIdx.x;
  if (i >= n8) return;
  const float4* p = (const float4*)in;
  float4 v0 = p[2 * i];
  float4 v1 = p[2 * i + 1];
  bf16x8 o;
  o[0] = (__bf16)v0.x; o[1] = (__bf16)v0.y; o[2] = (__bf16)v0.z; o[3] = (__bf16)v0.w;
  o[4] = (__bf16)v1.x; o[5] = (__bf16)v1.y; o[6] = (__bf16)v1.z; o[7] = (__bf16)v1.w;
  ((bf16x8*)out)[i] = o;
}

// W1'' 32-row block interleave: out-row r, b=r>>5, t=r&31:
//   src row = (b&1)*1024 + (b>>1)*32 + t
// => n-frag pairs (j=0 x_val block, j=1 res block) cover the SAME G columns.
__global__ void cast_w1_blk32(const float* __restrict__ in,
                              __bf16* __restrict__ out) {
  int i = blockIdx.x * blockDim.x + threadIdx.x;  // 2048*128 threads
  int orow = i >> 7;
  int chunk = i & 127;
  int b = orow >> 5, t = orow & 31;
  int srow = (b & 1) * 1024 + (b >> 1) * 32 + t;
  const float4* p = (const float4*)(in + ((size_t)srow << 10) + (chunk << 3));
  float4 v0 = p[0], v1 = p[1];
  bf16x8 o;
  o[0] = (__bf16)v0.x; o[1] = (__bf16)v0.y; o[2] = (__bf16)v0.z; o[3] = (__bf16)v0.w;
  o[4] = (__bf16)v1.x; o[5] = (__bf16)v1.y; o[6] = (__bf16)v1.z; o[7] = (__bf16)v1.w;
  *(bf16x8*)(out + ((size_t)orow << 10) + (chunk << 3)) = o;
}

// ---------------- GEMM core ----------------
// Stage one 256x32 K-tile of A and B into buffer BUF. 4 gloads per wave.
template <int BUF>
__device__ __forceinline__ void stage_tile(const __bf16*& pa, const __bf16*& pb,
                                           __bf16* smw) {
  __bf16* d = smw + BUF * BUF_ELEMS;
  gload_lds16(pa, d);
  gload_lds16(pa + 128 * KD, d + 4096);
  gload_lds16(pb, d + 8192);
  gload_lds16(pb + 128 * KD, d + 12288);
  pa += 32;
  pb += 32;
}

// 32x32x16 MFMA: A/B lane l: row/col = l&31, k = (l>>5)*8 + e.
// Per K-tile-32: 2 k-slices; reads 8 A + 4 B b128; 16 MFMA.
template <int BUF>
__device__ __forceinline__ void compute_tile(const __bf16* sm,
                                             int aoff0, int aoff1,
                                             int boff0, int boff1,
                                             f32x16 (&acc)[4][2]) {
  const __bf16* base = sm + BUF * BUF_ELEMS;
  bf16x8 a0[4], a1[4], b0[2], b1[2];
#pragma unroll
  for (int j = 0; j < 2; ++j) {
    b0[j] = *(const bf16x8*)(base + boff0 + j * 1024);
    b1[j] = *(const bf16x8*)(base + boff1 + j * 1024);
  }
#pragma unroll
  for (int i = 0; i < 4; ++i) {
    a0[i] = *(const bf16x8*)(base + aoff0 + i * 1024);
    a1[i] = *(const bf16x8*)(base + aoff1 + i * 1024);
  }
  __builtin_amdgcn_s_setprio(1);
#pragma unroll
  for (int i = 0; i < 4; ++i)
#pragma unroll
    for (int j = 0; j < 2; ++j)
      acc[i][j] = __builtin_amdgcn_mfma_f32_32x32x16_bf16(a0[i], b0[j], acc[i][j], 0, 0, 0);
#pragma unroll
  for (int i = 0; i < 4; ++i)
#pragma unroll
    for (int j = 0; j < 2; ++j)
      acc[i][j] = __builtin_amdgcn_mfma_f32_32x32x16_bf16(a1[i], b1[j], acc[i][j], 0, 0, 0);
  __builtin_amdgcn_s_setprio(0);
}

// Fills acc for the 256x256 tile at (m0, n0). A:[M][1024], B:[Nrows][1024].
__device__ __forceinline__ void gemm_core(const __bf16* __restrict__ A,
                                          const __bf16* __restrict__ B,
                                          __bf16* sm, long m0, long n0,
                                          f32x16 (&acc)[4][2]) {
  const int t = threadIdx.x;
  const int w = t >> 6;
  const int lane = t & 63;
  const int c31 = lane & 31;
  const int hi = lane >> 5;
  const int wr = w >> 2;  // 0..1 (M)
  const int wc = w & 3;   // 0..3 (N)

  // staging source (per thread, swizzled chunk: phys = logical ^ ((row>>1)&3))
  const int l = lane;
  const int stg_row = w * 16 + (l >> 2);
  const int stg_col = ((l & 3) ^ ((l >> 3) & 3)) << 3;
  const __bf16* pa = A + (m0 + stg_row) * KD + stg_col;
  const __bf16* pb = B + (n0 + stg_row) * KD + stg_col;
  __bf16* smw = sm + w * 512;  // wave-uniform LDS base (1024B per wave-instr)

  // fragment read offsets (elements). key = (row>>1)&3 = (c31>>1)&3.
  const int key = (c31 >> 1) & 3;
  const int ch0 = (hi ^ key) << 3;        // k-slice 0 chunk
  const int ch1 = ((2 + hi) ^ key) << 3;  // k-slice 1 chunk
  const int aoff0 = (wr * 128 + c31) * 32 + ch0;          // + i*1024
  const int aoff1 = (wr * 128 + c31) * 32 + ch1;
  const int boff0 = 8192 + (wc * 64 + c31) * 32 + ch0;    // + j*1024
  const int boff1 = 8192 + (wc * 64 + c31) * 32 + ch1;

#pragma unroll
  for (int i = 0; i < 4; ++i)
#pragma unroll
    for (int j = 0; j < 2; ++j)
      acc[i][j] = (f32x16){0.f, 0.f, 0.f, 0.f, 0.f, 0.f, 0.f, 0.f,
                           0.f, 0.f, 0.f, 0.f, 0.f, 0.f, 0.f, 0.f};

  // prologue: stage tiles 0,1
  stage_tile<0>(pa, pb, smw);
  stage_tile<1>(pa, pb, smw);

  // tiles 0..29: compute buf t%3, stage tile t+2 into buf (t+2)%3
  for (int it = 0; it < 10; ++it) {
    WAITB(4); stage_tile<2>(pa, pb, smw);
    compute_tile<0>(sm, aoff0, aoff1, boff0, boff1, acc);
    WAITB(4); stage_tile<0>(pa, pb, smw);
    compute_tile<1>(sm, aoff0, aoff1, boff0, boff1, acc);
    WAITB(4); stage_tile<1>(pa, pb, smw);
    compute_tile<2>(sm, aoff0, aoff1, boff0, boff1, acc);
  }
  // tail: tiles 30 (buf0), 31 (buf1)
  WAITB(4); compute_tile<0>(sm, aoff0, aoff1, boff0, boff1, acc);
  WAITB(0); compute_tile<1>(sm, aoff0, aoff1, boff0, boff1, acc);
}

// ---------------- GEMM1: Y = X @ W1''^T, paired-silu epilogue -> G bf16 -----
__global__ __launch_bounds__(512, 2)
void gemm1_silu(const __bf16* __restrict__ X, const __bf16* __restrict__ W1i,
                const float* __restrict__ in_b, __bf16* __restrict__ G) {
  __shared__ __bf16 sm[3 * BUF_ELEMS];
  // XCD-aware bijective swizzle: nwg = 128*8 = 1024, divisible by 8
  const int bid = blockIdx.x;
  const int swz = (bid & 7) * 128 + (bid >> 3);
  const long m0 = (long)(swz >> 3) * 256;
  const long n0 = (long)(swz & 7) * 256;

  f32x16 acc[4][2];
  gemm_core(X, W1i, sm, m0, n0, acc);

  const int lane = threadIdx.x & 63;
  const int w = threadIdx.x >> 6;
  const int wr = w >> 2, wc = w & 3;
  const int c31 = lane & 31;
  const int hi = lane >> 5;

  // G column for this wave's frag pair: even block j=0 (x_val), odd j=1 (res)
  const int gc = ((int)n0 >> 1) + wc * 32 + c31;
  const float bx = in_b[gc];
  const float br = in_b[1024 + gc];

#pragma unroll
  for (int i = 0; i < 4; ++i)
#pragma unroll
    for (int reg = 0; reg < 16; ++reg) {
      const int row = wr * 128 + i * 32 + (reg & 3) + 8 * (reg >> 2) + 4 * hi;
      float xv = acc[i][0][reg] + bx;
      float rs = acc[i][1][reg] + br;
      float e1 = __expf(-xv);
      float e2 = __expf(-rs);
      float g = xv * rs * __builtin_amdgcn_rcpf((1.0f + e1) * (1.0f + e2));
      G[(m0 + row) * 1024 + gc] = (__bf16)g;
    }
}

// ---------------- GEMM2: OUT = G @ W2^T + out_b (fp32) ----------------
__global__ __launch_bounds__(512, 2)
void gemm2_bias(const __bf16* __restrict__ G, const __bf16* __restrict__ W2,
                const float* __restrict__ out_b, float* __restrict__ OUT) {
  __shared__ __bf16 sm[3 * BUF_ELEMS];
  // nwg = 128*4 = 512, divisible by 8
  const int bid = blockIdx.x;
  const int swz = (bid & 7) * 64 + (bid >> 3);
  const long m0 = (long)(swz >> 2) * 256;
  const long n0 = (long)(swz & 3) * 256;

  f32x16 acc[4][2];
  gemm_core(G, W2, sm, m0, n0, acc);

  const int lane = threadIdx.x & 63;
  const int w = threadIdx.x >> 6;
  const int wr = w >> 2, wc = w & 3;
  const int c31 = lane & 31;
  const int hi = lane >> 5;

  float ob[2];
#pragma unroll
  for (int j = 0; j < 2; ++j)
    ob[j] = out_b[(int)n0 + wc * 64 + j * 32 + c31];
#pragma unroll
  for (int i = 0; i < 4; ++i)
#pragma unroll
    for (int j = 0; j < 2; ++j)
#pragma unroll
      for (int reg = 0; reg < 16; ++reg) {
        const int row = wr * 128 + i * 32 + (reg & 3) + 8 * (reg >> 2) + 4 * hi;
        const int col = (int)n0 + wc * 64 + j * 32 + c31;
        OUT[(m0 + row) * 1024 + col] = acc[i][j][reg] + ob[j];
      }
}

extern "C" void kernel_launch(void* const* d_in, const int* in_sizes, int n_in,
                              void* d_out, int out_size, void* d_ws, size_t ws_size,
                              hipStream_t stream) {
  const float* x = (const float*)d_in[0];
  const float* in_w = (const float*)d_in[1];
  const float* in_b = (const float*)d_in[2];
  const float* out_w = (const float*)d_in[3];
  const float* out_b = (const float*)d_in[4];
  // d_in[5..8] (dt_w, dt_b, A, Dp) are dead in the reference.

  char* ws = (char*)d_ws;
  __bf16* xb = (__bf16*)(ws);                       // 67108864 B
  __bf16* w1b = (__bf16*)(ws + (size_t)67108864);   //  4194304 B (blk32 interleaved)
  __bf16* w2b = (__bf16*)(ws + (size_t)71303168);   //  2097152 B
  __bf16* gb = (__bf16*)(ws + (size_t)73400320);    // 67108864 B

  cast_f32_to_bf16_x8<<<dim3(16384), 256, 0, stream>>>(x, xb, 33554432 / 8);
  cast_w1_blk32<<<dim3(1024), 256, 0, stream>>>(in_w, w1b);
  cast_f32_to_bf16_x8<<<dim3(512), 256, 0, stream>>>(out_w, w2b, 1048576 / 8);

  gemm1_silu<<<dim3(1024), 512, 0, stream>>>(xb, w1b, in_b, gb);
  gemm2_bias<<<dim3(512), 512, 0, stream>>>(gb, w2b, out_b, (float*)d_out);
}

// Round 6
// 266.072 us; speedup vs baseline: 1.1090x; 1.0198x over previous
//
#include <hip/hip_runtime.h>
#include <cstdint>

// MambaBlock: out = (silu(x@in_w[:1024]^T+b0) * silu(x@in_w[1024:]^T+b1)) @ out_w^T + out_b
// M = 32768, K = 1024. dt_w/dt_b/A/Dp are dead inputs.
//
// Core: 256x256 tile, BK=32, 512 threads (8 waves, 2Mx4N), triple-buffered LDS
// (96 KiB), prefetch depth 2, counted vmcnt(4), 32x32x16 MFMA, setprio, XCD
// swizzle, shuffle-free paired-silu epilogue (blk32-interleaved W1).
// Round 6: swizzle key fixed for the 32-row frag-read span:
//   key2(row) = ((row>>1) ^ (row>>4)) & 3
// (r5's (row>>1)&3 aliased lanes l/l+16 onto the same banks -> 1.26e7
// conflicts; key2 reproduces r2's measured-zero 16-lane slot pattern.)

typedef __bf16 bf16x8 __attribute__((ext_vector_type(8)));
typedef float f32x16 __attribute__((ext_vector_type(16)));

#define KD 1024
#define BUF_ELEMS 16384  // (256*32 A + 256*32 B) elems per buffer

__device__ __forceinline__ void gload_lds16(const void* g, void* lds_u) {
  __builtin_amdgcn_global_load_lds(
      (__attribute__((address_space(1))) void*)(uintptr_t)g,
      (__attribute__((address_space(3))) void*)(uint32_t)(uintptr_t)lds_u,
      16, 0, 0);
}

#define WAITB(N) do { \
  asm volatile("s_waitcnt vmcnt(" #N ")" ::: "memory"); \
  asm volatile("s_barrier" ::: "memory"); } while (0)

// ---------------- casts ----------------
__global__ void cast_f32_to_bf16_x8(const float* __restrict__ in,
                                    __bf16* __restrict__ out, int n8) {
  int i = blockIdx.x * blockDim.x + threadIdx.x;
  if (i >= n8) return;
  const float4* p = (const float4*)in;
  float4 v0 = p[2 * i];
  float4 v1 = p[2 * i + 1];
  bf16x8 o;
  o[0] = (__bf16)v0.x; o[1] = (__bf16)v0.y; o[2] = (__bf16)v0.z; o[3] = (__bf16)v0.w;
  o[4] = (__bf16)v1.x; o[5] = (__bf16)v1.y; o[6] = (__bf16)v1.z; o[7] = (__bf16)v1.w;
  ((bf16x8*)out)[i] = o;
}

// W1'' 32-row block interleave: out-row r, b=r>>5, t=r&31:
//   src row = (b&1)*1024 + (b>>1)*32 + t
// => n-frag pairs (j=0 x_val block, j=1 res block) cover the SAME G columns.
__global__ void cast_w1_blk32(const float* __restrict__ in,
                              __bf16* __restrict__ out) {
  int i = blockIdx.x * blockDim.x + threadIdx.x;  // 2048*128 threads
  int orow = i >> 7;
  int chunk = i & 127;
  int b = orow >> 5, t = orow & 31;
  int srow = (b & 1) * 1024 + (b >> 1) * 32 + t;
  const float4* p = (const float4*)(in + ((size_t)srow << 10) + (chunk << 3));
  float4 v0 = p[0], v1 = p[1];
  bf16x8 o;
  o[0] = (__bf16)v0.x; o[1] = (__bf16)v0.y; o[2] = (__bf16)v0.z; o[3] = (__bf16)v0.w;
  o[4] = (__bf16)v1.x; o[5] = (__bf16)v1.y; o[6] = (__bf16)v1.z; o[7] = (__bf16)v1.w;
  *(bf16x8*)(out + ((size_t)orow << 10) + (chunk << 3)) = o;
}

// ---------------- GEMM core ----------------
// Stage one 256x32 K-tile of A and B into buffer BUF. 4 gloads per wave.
template <int BUF>
__device__ __forceinline__ void stage_tile(const __bf16*& pa, const __bf16*& pb,
                                           __bf16* smw) {
  __bf16* d = smw + BUF * BUF_ELEMS;
  gload_lds16(pa, d);
  gload_lds16(pa + 128 * KD, d + 4096);
  gload_lds16(pb, d + 8192);
  gload_lds16(pb + 128 * KD, d + 12288);
  pa += 32;
  pb += 32;
}

// 32x32x16 MFMA. Per K-tile-32: 2 k-slices; 8 A + 4 B b128 reads; 16 MFMA.
// Chunk swizzle: phys = logical ^ key2(row); per frag parity the chunk offset
// alternates between o0 and o1 = o0^16 (key2 flips by 2 when frag idx is odd).
template <int BUF>
__device__ __forceinline__ void compute_tile(const __bf16* sm,
                                             int aRow, int bRow,
                                             int o0, int o1,
                                             f32x16 (&acc)[4][2]) {
  const __bf16* base = sm + BUF * BUF_ELEMS;
  bf16x8 a0[4], a1[4], b0[2], b1[2];
  // j even: ks0 -> o0, ks1 -> o1 ; j odd: swapped
  b0[0] = *(const bf16x8*)(base + bRow + o0);
  b1[0] = *(const bf16x8*)(base + bRow + o1);
  b0[1] = *(const bf16x8*)(base + bRow + 1024 + o1);
  b1[1] = *(const bf16x8*)(base + bRow + 1024 + o0);
#pragma unroll
  for (int i = 0; i < 4; ++i) {
    const int e0 = (i & 1) ? o1 : o0;
    const int e1 = (i & 1) ? o0 : o1;
    a0[i] = *(const bf16x8*)(base + aRow + i * 1024 + e0);
    a1[i] = *(const bf16x8*)(base + aRow + i * 1024 + e1);
  }
  __builtin_amdgcn_s_setprio(1);
#pragma unroll
  for (int i = 0; i < 4; ++i)
#pragma unroll
    for (int j = 0; j < 2; ++j)
      acc[i][j] = __builtin_amdgcn_mfma_f32_32x32x16_bf16(a0[i], b0[j], acc[i][j], 0, 0, 0);
#pragma unroll
  for (int i = 0; i < 4; ++i)
#pragma unroll
    for (int j = 0; j < 2; ++j)
      acc[i][j] = __builtin_amdgcn_mfma_f32_32x32x16_bf16(a1[i], b1[j], acc[i][j], 0, 0, 0);
  __builtin_amdgcn_s_setprio(0);
}

// Fills acc for the 256x256 tile at (m0, n0). A:[M][1024], B:[Nrows][1024].
__device__ __forceinline__ void gemm_core(const __bf16* __restrict__ A,
                                          const __bf16* __restrict__ B,
                                          __bf16* sm, long m0, long n0,
                                          f32x16 (&acc)[4][2]) {
  const int t = threadIdx.x;
  const int w = t >> 6;
  const int lane = t & 63;
  const int c31 = lane & 31;
  const int hi = lane >> 5;
  const int wr = w >> 2;  // 0..1 (M)
  const int wc = w & 3;   // 0..3 (N)

  // staging source: lane l covers LDS row w*16+(l>>2), phys slot l&3, which
  // must hold logical chunk (l&3) ^ key2(row); key2 = ((l>>3)&3) ^ (w&3).
  const int l = lane;
  const int stg_row = w * 16 + (l >> 2);
  const int stg_col = ((l & 3) ^ ((l >> 3) & 3) ^ (w & 3)) << 3;
  const __bf16* pa = A + (m0 + stg_row) * KD + stg_col;
  const __bf16* pb = B + (n0 + stg_row) * KD + stg_col;
  __bf16* smw = sm + w * 512;  // wave-uniform LDS base (1024B per wave-instr)

  // fragment read offsets. key_base = ((c31>>1)&3) ^ ((c31>>4)&1); frag idx
  // parity flips key by 2 (row bit 5 via r>>4). o1 = o0 ^ 16 elems.
  const int key_base = ((c31 >> 1) & 3) ^ ((c31 >> 4) & 1);
  const int o0 = (hi ^ key_base) << 3;
  const int o1 = o0 ^ 16;
  const int aRow = (wr * 128 + c31) * 32;          // + i*1024
  const int bRow = 8192 + (wc * 64 + c31) * 32;    // + j*1024

#pragma unroll
  for (int i = 0; i < 4; ++i)
#pragma unroll
    for (int j = 0; j < 2; ++j)
      acc[i][j] = (f32x16){0.f, 0.f, 0.f, 0.f, 0.f, 0.f, 0.f, 0.f,
                           0.f, 0.f, 0.f, 0.f, 0.f, 0.f, 0.f, 0.f};

  // prologue: stage tiles 0,1
  stage_tile<0>(pa, pb, smw);
  stage_tile<1>(pa, pb, smw);

  // tiles 0..29: compute buf t%3, stage tile t+2 into buf (t+2)%3
  for (int it = 0; it < 10; ++it) {
    WAITB(4); stage_tile<2>(pa, pb, smw);
    compute_tile<0>(sm, aRow, bRow, o0, o1, acc);
    WAITB(4); stage_tile<0>(pa, pb, smw);
    compute_tile<1>(sm, aRow, bRow, o0, o1, acc);
    WAITB(4); stage_tile<1>(pa, pb, smw);
    compute_tile<2>(sm, aRow, bRow, o0, o1, acc);
  }
  // tail: tiles 30 (buf0), 31 (buf1)
  WAITB(4); compute_tile<0>(sm, aRow, bRow, o0, o1, acc);
  WAITB(0); compute_tile<1>(sm, aRow, bRow, o0, o1, acc);
}

// ---------------- GEMM1: Y = X @ W1''^T, paired-silu epilogue -> G bf16 -----
__global__ __launch_bounds__(512, 2)
void gemm1_silu(const __bf16* __restrict__ X, const __bf16* __restrict__ W1i,
                const float* __restrict__ in_b, __bf16* __restrict__ G) {
  __shared__ __bf16 sm[3 * BUF_ELEMS];
  // XCD-aware bijective swizzle: nwg = 128*8 = 1024, divisible by 8
  const int bid = blockIdx.x;
  const int swz = (bid & 7) * 128 + (bid >> 3);
  const long m0 = (long)(swz >> 3) * 256;
  const long n0 = (long)(swz & 7) * 256;

  f32x16 acc[4][2];
  gemm_core(X, W1i, sm, m0, n0, acc);

  const int lane = threadIdx.x & 63;
  const int w = threadIdx.x >> 6;
  const int wr = w >> 2, wc = w & 3;
  const int c31 = lane & 31;
  const int hi = lane >> 5;

  // G column for this wave's frag pair: even block j=0 (x_val), odd j=1 (res)
  const int gc = ((int)n0 >> 1) + wc * 32 + c31;
  const float bx = in_b[gc];
  const float br = in_b[1024 + gc];

#pragma unroll
  for (int i = 0; i < 4; ++i)
#pragma unroll
    for (int reg = 0; reg < 16; ++reg) {
      const int row = wr * 128 + i * 32 + (reg & 3) + 8 * (reg >> 2) + 4 * hi;
      float xv = acc[i][0][reg] + bx;
      float rs = acc[i][1][reg] + br;
      float e1 = __expf(-xv);
      float e2 = __expf(-rs);
      float g = xv * rs * __builtin_amdgcn_rcpf((1.0f + e1) * (1.0f + e2));
      G[(m0 + row) * 1024 + gc] = (__bf16)g;
    }
}

// ---------------- GEMM2: OUT = G @ W2^T + out_b (fp32) ----------------
__global__ __launch_bounds__(512, 2)
void gemm2_bias(const __bf16* __restrict__ G, const __bf16* __restrict__ W2,
                const float* __restrict__ out_b, float* __restrict__ OUT) {
  __shared__ __bf16 sm[3 * BUF_ELEMS];
  // nwg = 128*4 = 512, divisible by 8
  const int bid = blockIdx.x;
  const int swz = (bid & 7) * 64 + (bid >> 3);
  const long m0 = (long)(swz >> 2) * 256;
  const long n0 = (long)(swz & 3) * 256;

  f32x16 acc[4][2];
  gemm_core(G, W2, sm, m0, n0, acc);

  const int lane = threadIdx.x & 63;
  const int w = threadIdx.x >> 6;
  const int wr = w >> 2, wc = w & 3;
  const int c31 = lane & 31;
  const int hi = lane >> 5;

  float ob[2];
#pragma unroll
  for (int j = 0; j < 2; ++j)
    ob[j] = out_b[(int)n0 + wc * 64 + j * 32 + c31];
#pragma unroll
  for (int i = 0; i < 4; ++i)
#pragma unroll
    for (int j = 0; j < 2; ++j)
#pragma unroll
      for (int reg = 0; reg < 16; ++reg) {
        const int row = wr * 128 + i * 32 + (reg & 3) + 8 * (reg >> 2) + 4 * hi;
        const int col = (int)n0 + wc * 64 + j * 32 + c31;
        OUT[(m0 + row) * 1024 + col] = acc[i][j][reg] + ob[j];
      }
}

extern "C" void kernel_launch(void* const* d_in, const int* in_sizes, int n_in,
                              void* d_out, int out_size, void* d_ws, size_t ws_size,
                              hipStream_t stream) {
  const float* x = (const float*)d_in[0];
  const float* in_w = (const float*)d_in[1];
  const float* in_b = (const float*)d_in[2];
  const float* out_w = (const float*)d_in[3];
  const float* out_b = (const float*)d_in[4];
  // d_in[5..8] (dt_w, dt_b, A, Dp) are dead in the reference.

  char* ws = (char*)d_ws;
  __bf16* xb = (__bf16*)(ws);                       // 67108864 B
  __bf16* w1b = (__bf16*)(ws + (size_t)67108864);   //  4194304 B (blk32 interleaved)
  __bf16* w2b = (__bf16*)(ws + (size_t)71303168);   //  2097152 B
  __bf16* gb = (__bf16*)(ws + (size_t)73400320);    // 67108864 B

  cast_f32_to_bf16_x8<<<dim3(16384), 256, 0, stream>>>(x, xb, 33554432 / 8);
  cast_w1_blk32<<<dim3(1024), 256, 0, stream>>>(in_w, w1b);
  cast_f32_to_bf16_x8<<<dim3(512), 256, 0, stream>>>(out_w, w2b, 1048576 / 8);

  gemm1_silu<<<dim3(1024), 512, 0, stream>>>(xb, w1b, in_b, gb);
  gemm2_bias<<<dim3(512), 512, 0, stream>>>(gb, w2b, out_b, (float*)d_out);
}